// Round 9
// baseline (354.379 us; speedup 1.0000x reference)
//
#include <hip/hip_runtime.h>
#include <hip/hip_bf16.h>

#define N_ROWS 262144
#define IN_DIM 64
#define HID 256
#define EMB 128
#define OUT_DIM 64
#define NSEG 1024
#define ROWS_B 128         // rows per block in k1/k3
#define MT 8               // row-tiles per wave (ROWS_B/16) -- every wave covers all rows
#define NWAVE 4            // waves per block (256 threads): C=4 col-groups -> half the LDS A-traffic of C=8
#define LDS_S 264          // halves per LDS row (256 + 8 pad -> stride 33 slots == 1 mod 8: uniform banks)
#define CHUNK 1024         // rows per k_scatter block
#define NSLOTS (2 * (N_ROWS / CHUNK))   // 512 partial slots

typedef _Float16 h16;
typedef _Float16 h16x8 __attribute__((ext_vector_type(8)));
typedef _Float16 h16x4 __attribute__((ext_vector_type(4)));
typedef float f32x4 __attribute__((ext_vector_type(4)));

// ---------------- prep kernels (round-6 proven versions) ----------------

__global__ void k_max(const int* __restrict__ aisle, int* __restrict__ maxA) {
    int v = 0;
    for (int i = blockIdx.x * blockDim.x + threadIdx.x; i < N_ROWS; i += gridDim.x * blockDim.x)
        v = max(v, aisle[i]);
#pragma unroll
    for (int off = 32; off > 0; off >>= 1) v = max(v, __shfl_down(v, off));
    __shared__ int red[4];
    if ((threadIdx.x & 63) == 0) red[threadIdx.x >> 6] = v;
    __syncthreads();
    if (threadIdx.x == 0) {
        int m = red[0];
        for (int i = 1; i < 4; ++i) m = max(m, red[i]);
        atomicMax(maxA, m);
    }
}

// Fragment-order weight layout: for n-tile t, k-step kt, the 64 lanes' h16x8
// fragments are CONTIGUOUS: halves offset = t*16*K + kt*512 + lane*8, where
// lane = l4*16 + l15 and the fragment holds W[k = kt*32 + l4*8 + j][n = t*16 + l15].
// A wave's (t,kt) load is one contiguous 1024B chunk -> perfectly coalesced.
__device__ __forceinline__ void frag_nk(int o, int K, int& n, int& k) {
    int tile = o / (16 * K);
    int r = o - tile * 16 * K;
    n = tile * 16 + ((r >> 3) & 15);
    k = (r >> 9) * 32 + (((r >> 7) & 3) << 3) + (r & 7);
}

__global__ void k_prep_weights(const float* __restrict__ W1, const float* __restrict__ W2,
                               const float* __restrict__ W3, const float* __restrict__ A1f,
                               const float* __restrict__ A2f, const float* __restrict__ A3f,
                               h16* __restrict__ W1t, h16* __restrict__ W2t, h16* __restrict__ W3t,
                               h16* __restrict__ A1t, h16* __restrict__ A2t, h16* __restrict__ A3t) {
    int idx = blockIdx.x * 256 + threadIdx.x;      // total 262144 threads
    int n, k;
    if (idx < 16384)       { int o = idx;          frag_nk(o, 64, n, k);  W1t[o] = (h16)W1[k * 256 + n]; }
    else if (idx < 81920)  { int o = idx - 16384;  frag_nk(o, 256, n, k); W2t[o] = (h16)W2[k * 256 + n]; }
    else if (idx < 114688) { int o = idx - 81920;  frag_nk(o, 256, n, k); W3t[o] = (h16)W3[k * 128 + n]; }
    else if (idx < 180224) { int o = idx - 114688; frag_nk(o, 256, n, k); A1t[o] = (h16)A1f[k * 256 + n]; }
    else if (idx < 245760) { int o = idx - 180224; frag_nk(o, 256, n, k); A2t[o] = (h16)A2f[k * 256 + n]; }
    else                   { int o = idx - 245760; frag_nk(o, 256, n, k); A3t[o] = (h16)A3f[k * 64  + n]; }
}

// ---------------- fused MLP layer, IN-PLACE, 4 waves x (128 rows x 64 cols) ----------------
// S: [128 rows][K] fp16, stride LDS_S. Computes lrelu?(S @ W^T + bias) back into S.
// Every wave reads ALL rows/k of S, then barrier, then epilogue overwrites its
// 64-col slice, then barrier. Weights in fragment-order: wave's (nt,kt) fragment
// load = contiguous 1024B, depth-3 prefetched (covers L2 latency).
// Swapped-operand MFMA: mfma(w, a, acc) -> D[n][m].
template <int K, int NOUT, bool ACT>
__device__ __forceinline__ void mlp_layer_ip(const h16* __restrict__ Wt,
                                             const float* __restrict__ bias,
                                             h16* __restrict__ S,
                                             int lane, int wave) {
    constexpr int NW = NOUT / NWAVE;   // cols per wave (64)
    constexpr int NT = NW / 16;        // n-tiles per wave (4)
    constexpr int KT = K / 32;         // k-steps
    const int l15 = lane & 15, l4 = lane >> 4;
    f32x4 acc[MT][NT];
#pragma unroll
    for (int mt = 0; mt < MT; ++mt)
#pragma unroll
        for (int nt = 0; nt < NT; ++nt)
#pragma unroll
            for (int j = 0; j < 4; ++j) acc[mt][nt][j] = 0.f;

    const h16* wb[NT];
#pragma unroll
    for (int nt = 0; nt < NT; ++nt)
        wb[nt] = Wt + (size_t)(wave * NT + nt) * 16 * K + lane * 8;

    h16x8 b0[NT], b1[NT], b2[NT];
#pragma unroll
    for (int nt = 0; nt < NT; ++nt) b0[nt] = *(const h16x8*)wb[nt];
    if (KT > 1) {
#pragma unroll
        for (int nt = 0; nt < NT; ++nt) b1[nt] = *(const h16x8*)(wb[nt] + 512);
    }
    if (KT > 2) {
#pragma unroll
        for (int nt = 0; nt < NT; ++nt) b2[nt] = *(const h16x8*)(wb[nt] + 1024);
    }

#pragma unroll
    for (int kt = 0; kt < KT; ++kt) {
        h16x8 bc[NT];
#pragma unroll
        for (int nt = 0; nt < NT; ++nt) bc[nt] = b0[nt];
#pragma unroll
        for (int nt = 0; nt < NT; ++nt) b0[nt] = b1[nt];
#pragma unroll
        for (int nt = 0; nt < NT; ++nt) b1[nt] = b2[nt];
        if (kt + 3 < KT) {
#pragma unroll
            for (int nt = 0; nt < NT; ++nt) b2[nt] = *(const h16x8*)(wb[nt] + (kt + 3) * 512);
        }
        __builtin_amdgcn_s_setprio(1);
#pragma unroll
        for (int mt = 0; mt < MT; ++mt) {
            h16x8 a = *(const h16x8*)&S[(mt * 16 + l15) * LDS_S + kt * 32 + l4 * 8];
#pragma unroll
            for (int nt = 0; nt < NT; ++nt)
                acc[mt][nt] = __builtin_amdgcn_mfma_f32_16x16x32_f16(bc[nt], a, acc[mt][nt], 0, 0, 0);
        }
        __builtin_amdgcn_s_setprio(0);
    }

    __syncthreads();   // all reads of S complete across the block

#pragma unroll
    for (int nt = 0; nt < NT; ++nt) {
        const int cb = wave * NW + nt * 16 + l4 * 4;
        const f32x4 bias4 = *(const f32x4*)&bias[cb];
#pragma unroll
        for (int mt = 0; mt < MT; ++mt) {
            f32x4 v = acc[mt][nt] + bias4;
            if (ACT) {
#pragma unroll
                for (int j = 0; j < 4; ++j) v[j] = fmaxf(v[j], 0.01f * v[j]);
            }
            h16x4 hv;
#pragma unroll
            for (int j = 0; j < 4; ++j) hv[j] = (h16)v[j];
            *(h16x4*)&S[(mt * 16 + l15) * LDS_S + cb] = hv;
        }
    }
    __syncthreads();   // new acts visible
}

// Final k1 layer: K=256 -> 128 cols (32 cols/wave, NT=2), direct global h16 store.
__device__ __forceinline__ void mlp_layer_out_h16(const h16* __restrict__ Wt,
                                                  const float* __restrict__ bias,
                                                  const h16* __restrict__ S,
                                                  h16* __restrict__ gout, int row0,
                                                  int lane, int wave) {
    const int l15 = lane & 15, l4 = lane >> 4;
    f32x4 acc[MT][2];
#pragma unroll
    for (int mt = 0; mt < MT; ++mt)
#pragma unroll
        for (int nt = 0; nt < 2; ++nt)
#pragma unroll
            for (int j = 0; j < 4; ++j) acc[mt][nt][j] = 0.f;

    const h16* wb[2];
#pragma unroll
    for (int nt = 0; nt < 2; ++nt)
        wb[nt] = Wt + (size_t)(wave * 2 + nt) * 16 * 256 + lane * 8;

    h16x8 b0[2], b1[2], b2[2];
#pragma unroll
    for (int nt = 0; nt < 2; ++nt) { b0[nt] = *(const h16x8*)wb[nt];
                                     b1[nt] = *(const h16x8*)(wb[nt] + 512);
                                     b2[nt] = *(const h16x8*)(wb[nt] + 1024); }
#pragma unroll
    for (int kt = 0; kt < 8; ++kt) {
        h16x8 bc[2];
#pragma unroll
        for (int nt = 0; nt < 2; ++nt) bc[nt] = b0[nt];
#pragma unroll
        for (int nt = 0; nt < 2; ++nt) b0[nt] = b1[nt];
#pragma unroll
        for (int nt = 0; nt < 2; ++nt) b1[nt] = b2[nt];
        if (kt + 3 < 8) {
#pragma unroll
            for (int nt = 0; nt < 2; ++nt) b2[nt] = *(const h16x8*)(wb[nt] + (kt + 3) * 512);
        }
        __builtin_amdgcn_s_setprio(1);
#pragma unroll
        for (int mt = 0; mt < MT; ++mt) {
            h16x8 a = *(const h16x8*)&S[(mt * 16 + l15) * LDS_S + kt * 32 + l4 * 8];
#pragma unroll
            for (int nt = 0; nt < 2; ++nt)
                acc[mt][nt] = __builtin_amdgcn_mfma_f32_16x16x32_f16(bc[nt], a, acc[mt][nt], 0, 0, 0);
        }
        __builtin_amdgcn_s_setprio(0);
    }

#pragma unroll
    for (int nt = 0; nt < 2; ++nt) {
        const int cb = wave * 32 + nt * 16 + l4 * 4;
        const f32x4 bias4 = *(const f32x4*)&bias[cb];
#pragma unroll
        for (int mt = 0; mt < MT; ++mt) {
            f32x4 v = acc[mt][nt] + bias4;
            h16x4 hv;
#pragma unroll
            for (int j = 0; j < 4; ++j) hv[j] = (h16)v[j];
            *(h16x4*)&gout[(size_t)(row0 + mt * 16 + l15) * 128 + cb] = hv;
        }
    }
}

// ---------------- phase 1: x -> h ----------------
__global__ __launch_bounds__(256, 2) void k1(const float* __restrict__ x,
                                             const h16* __restrict__ W1t, const float* __restrict__ b1,
                                             const h16* __restrict__ W2t, const float* __restrict__ b2,
                                             const h16* __restrict__ W3t, const float* __restrict__ b3,
                                             h16* __restrict__ hbuf) {
    __shared__ __align__(16) h16 S[ROWS_B * LDS_S];
    const int tid = threadIdx.x, lane = tid & 63, wave = tid >> 6;
    const int row0 = blockIdx.x * ROWS_B;

    for (int i = tid; i < 512; i += 256) {   // 4 slots/row, 16 floats each
        const int r = i >> 2, c16 = (i & 3) * 16;
        const float* src = &x[(size_t)(row0 + r) * 64 + c16];
        f32x4 v0 = *(const f32x4*)&src[0];
        f32x4 v1 = *(const f32x4*)&src[4];
        f32x4 v2 = *(const f32x4*)&src[8];
        f32x4 v3 = *(const f32x4*)&src[12];
        h16x8 h0, h1;
#pragma unroll
        for (int j = 0; j < 4; ++j) { h0[j] = (h16)v0[j]; h0[4 + j] = (h16)v1[j];
                                      h1[j] = (h16)v2[j]; h1[4 + j] = (h16)v3[j]; }
        *(h16x8*)&S[r * LDS_S + c16]     = h0;
        *(h16x8*)&S[r * LDS_S + c16 + 8] = h1;
    }
    __syncthreads();

    mlp_layer_ip<64, 256, true>(W1t, b1, S, lane, wave);
    mlp_layer_ip<256, 256, true>(W2t, b2, S, lane, wave);
    mlp_layer_out_h16(W3t, b3, S, hbuf, row0, lane, wave);
}

// ---------------- phase 2: counting-sort + owner-computes segment sums (round-6 proven) ----------------
__global__ __launch_bounds__(256) void k_scatter(const h16* __restrict__ hbuf,
                                                 const int* __restrict__ aisle,
                                                 const int* __restrict__ batch,
                                                 float* __restrict__ partials,
                                                 float* __restrict__ pcount,
                                                 int* __restrict__ bvmap) {
    __shared__ int la[CHUNK], lb[CHUNK], rankv[CHUNK], rowlist[CHUNK];
    __shared__ int hist[128], scan[128];
    const int tid = threadIdx.x;
    const int row0 = blockIdx.x * CHUNK;

    if (tid < 128) hist[tid] = 0;
    for (int i = tid; i < CHUNK; i += 256) { la[i] = aisle[row0 + i]; lb[i] = batch[row0 + i]; }
    __syncthreads();

    const int bLo = lb[0], bHi = lb[CHUNK - 1];

    for (int i = tid; i < CHUNK; i += 256) {
        int slot = min(lb[i] - bLo, 1);
        rankv[i] = atomicAdd(&hist[slot * 64 + la[i]], 1);
    }
    __syncthreads();
    if (tid < 128) scan[tid] = hist[tid];
    __syncthreads();
#pragma unroll
    for (int st = 1; st < 128; st <<= 1) {
        int v = 0;
        if (tid < 128 && tid >= st) v = scan[tid - st];
        __syncthreads();
        if (tid < 128) scan[tid] += v;
        __syncthreads();
    }
    for (int i = tid; i < CHUNK; i += 256) {
        int bin = min(lb[i] - bLo, 1) * 64 + la[i];
        rowlist[scan[bin] - hist[bin] + rankv[i]] = i;
    }
    __syncthreads();

    const int a_own = tid >> 2, cg = tid & 3;
    for (int slot = 0; slot < 2; ++slot) {
        const int sid = blockIdx.x * 2 + slot;
        const int bv = bLo + slot;
        if (bv > bHi) { if (tid == 0) bvmap[sid] = -1; continue; }

        const int bin = slot * 64 + a_own;
        const int s1 = scan[bin];
        const int s0 = s1 - hist[bin];

        float acc[32];
#pragma unroll
        for (int j = 0; j < 32; ++j) acc[j] = 0.f;

        for (int idx = s0; idx < s1; ++idx) {
            const int r = rowlist[idx];
            const h16x8* src = (const h16x8*)&hbuf[(size_t)(row0 + r) * 128 + cg * 32];
            h16x8 v0 = src[0], v1 = src[1], v2 = src[2], v3 = src[3];
#pragma unroll
            for (int j = 0; j < 8; ++j) {
                acc[j]      += (float)v0[j];
                acc[8 + j]  += (float)v1[j];
                acc[16 + j] += (float)v2[j];
                acc[24 + j] += (float)v3[j];
            }
        }
        float* dst = &partials[(size_t)sid * 8192 + tid * 32];
#pragma unroll
        for (int g2 = 0; g2 < 8; ++g2) *(f32x4*)&dst[g2 * 4] = *(const f32x4*)&acc[g2 * 4];
        if (cg == 0) pcount[sid * 64 + a_own] = (float)(s1 - s0);
        if (tid == 0) bvmap[sid] = bv;
    }
}

// ---------------- phase 2b: reduce partials -> fp16 means (round-6 proven) ----------------
__global__ __launch_bounds__(128) void k_means(const float* __restrict__ partials,
                                               const float* __restrict__ pcount,
                                               const int* __restrict__ bvmap,
                                               h16* __restrict__ means,
                                               const int* __restrict__ maxA) {
    __shared__ int sbv[NSLOTS];
    const int b = blockIdx.x >> 6, a = blockIdx.x & 63;
    const int tid = threadIdx.x;
    const int mult = *maxA + 1;
    for (int i = tid; i < NSLOTS; i += 128) sbv[i] = bvmap[i];
    __syncthreads();
    if (a >= mult) return;

    float sum = 0.f, cnt = 0.f;
    for (int s = 0; s < NSLOTS; ++s) {
        if (sbv[s] == b) {
            sum += partials[(size_t)s * 8192 + a * 128 + tid];
            cnt += pcount[s * 64 + a];   // broadcast load
        }
    }
    means[(size_t)(b * mult + a) * 128 + tid] = (h16)(sum / fmaxf(cnt, 1.0f));
}

// ---------------- phase 3: concat(h, mean) -> out ----------------
__global__ __launch_bounds__(256, 2) void k3(const h16* __restrict__ hbuf,
                                             const int* __restrict__ aisle,
                                             const int* __restrict__ batch,
                                             const h16* __restrict__ means,
                                             const h16* __restrict__ A1t, const float* __restrict__ c1,
                                             const h16* __restrict__ A2t, const float* __restrict__ c2,
                                             const h16* __restrict__ A3t, const float* __restrict__ c3,
                                             float* __restrict__ out, const int* __restrict__ maxA) {
    __shared__ __align__(16) h16 S[ROWS_B * LDS_S];
    const int tid = threadIdx.x, lane = tid & 63, wave = tid >> 6;
    const int row0 = blockIdx.x * ROWS_B;
    const int mult = *maxA + 1;

    for (int i = tid; i < 512; i += 256) {   // stage h + mean; 4 slots/row, 32 halves each
        const int r = i >> 2, p = i & 3;
        const int g = row0 + r;
        const h16x8* hs = (const h16x8*)&hbuf[(size_t)g * 128 + p * 32];
        h16x8* hd = (h16x8*)&S[r * LDS_S + p * 32];
        hd[0] = hs[0]; hd[1] = hs[1]; hd[2] = hs[2]; hd[3] = hs[3];
        const int id = aisle[g] + batch[g] * mult;
        const h16x8* ms = (const h16x8*)&means[(size_t)id * 128 + p * 32];
        h16x8* md = (h16x8*)&S[r * LDS_S + 128 + p * 32];
        md[0] = ms[0]; md[1] = ms[1]; md[2] = ms[2]; md[3] = ms[3];
    }
    __syncthreads();

    mlp_layer_ip<256, 256, true>(A1t, c1, S, lane, wave);
    mlp_layer_ip<256, 256, true>(A2t, c2, S, lane, wave);

    // final layer: K=256 -> 64 cols; 4 waves x 16 cols, full K per wave (no k-split,
    // no LDS reduce), fp32 f32x4 stores
    {
        const int l15 = lane & 15, l4 = lane >> 4;
        f32x4 acc4[MT];
#pragma unroll
        for (int mt = 0; mt < MT; ++mt)
#pragma unroll
            for (int j = 0; j < 4; ++j) acc4[mt][j] = 0.f;

        const h16* wb = A3t + (size_t)wave * 16 * 256 + lane * 8;
        h16x8 b0 = *(const h16x8*)wb;
        h16x8 b1 = *(const h16x8*)(wb + 512);
        h16x8 b2 = *(const h16x8*)(wb + 1024);
#pragma unroll
        for (int kt = 0; kt < 8; ++kt) {
            h16x8 bc = b0;
            b0 = b1;
            b1 = b2;
            if (kt + 3 < 8) b2 = *(const h16x8*)(wb + (kt + 3) * 512);
            __builtin_amdgcn_s_setprio(1);
#pragma unroll
            for (int mt = 0; mt < MT; ++mt) {
                h16x8 a = *(const h16x8*)&S[(mt * 16 + l15) * LDS_S + kt * 32 + l4 * 8];
                acc4[mt] = __builtin_amdgcn_mfma_f32_16x16x32_f16(bc, a, acc4[mt], 0, 0, 0);
            }
            __builtin_amdgcn_s_setprio(0);
        }
        const f32x4 bias4 = *(const f32x4*)&c3[wave * 16 + l4 * 4];
#pragma unroll
        for (int mt = 0; mt < MT; ++mt) {
            f32x4 v = acc4[mt] + bias4;
            *(f32x4*)&out[(size_t)(row0 + mt * 16 + l15) * 64 + wave * 16 + l4 * 4] = v;
        }
    }
}

// ---------------- host launch ----------------
extern "C" void kernel_launch(void* const* d_in, const int* in_sizes, int n_in,
                              void* d_out, int out_size, void* d_ws, size_t ws_size,
                              hipStream_t stream) {
    const float* x     = (const float*)d_in[0];
    const int*   aisle = (const int*)d_in[1];
    const int*   batch = (const int*)d_in[2];
    const float* W1 = (const float*)d_in[3];  const float* b1 = (const float*)d_in[4];
    const float* W2 = (const float*)d_in[5];  const float* b2 = (const float*)d_in[6];
    const float* W3 = (const float*)d_in[7];  const float* b3 = (const float*)d_in[8];
    const float* A1 = (const float*)d_in[9];  const float* c1 = (const float*)d_in[10];
    const float* A2 = (const float*)d_in[11]; const float* c2 = (const float*)d_in[12];
    const float* A3 = (const float*)d_in[13]; const float* c3 = (const float*)d_in[14];
    float* out = (float*)d_out;

    char* w = (char*)d_ws;
    size_t off = 0;
    h16*   hbuf     = (h16*)(w + off);   off += (size_t)N_ROWS * 128 * sizeof(h16);       // 64 MB
    float* partials = (float*)(w + off); off += (size_t)NSLOTS * 8192 * sizeof(float);    // 16 MB
    float* pcount   = (float*)(w + off); off += NSLOTS * 64 * sizeof(float);
    int*   bvmap    = (int*)(w + off);   off += NSLOTS * sizeof(int);
    h16*   means    = (h16*)(w + off);   off += NSEG * 128 * sizeof(h16);
    h16*   W1t      = (h16*)(w + off);   off += 16384 * sizeof(h16);
    h16*   W2t      = (h16*)(w + off);   off += 65536 * sizeof(h16);
    h16*   W3t      = (h16*)(w + off);   off += 32768 * sizeof(h16);
    h16*   A1t      = (h16*)(w + off);   off += 65536 * sizeof(h16);
    h16*   A2t      = (h16*)(w + off);   off += 65536 * sizeof(h16);
    h16*   A3t      = (h16*)(w + off);   off += 16384 * sizeof(h16);
    int*   maxA     = (int*)(w + off);   off += 256;

    hipMemsetAsync(maxA, 0, sizeof(int), stream);

    k_max<<<256, 256, 0, stream>>>(aisle, maxA);
    k_prep_weights<<<1024, 256, 0, stream>>>(W1, W2, W3, A1, A2, A3, W1t, W2t, W3t, A1t, A2t, A3t);
    k1<<<N_ROWS / ROWS_B, 256, 0, stream>>>(x, W1t, b1, W2t, b2, W3t, b3, hbuf);
    k_scatter<<<N_ROWS / CHUNK, 256, 0, stream>>>(hbuf, aisle, batch, partials, pcount, bvmap);
    k_means<<<16 * 64, 128, 0, stream>>>(partials, pcount, bvmap, means, maxA);
    k3<<<N_ROWS / ROWS_B, 256, 0, stream>>>(hbuf, aisle, batch, means, A1t, c1, A2t, c2, A3t, c3,
                                            out, maxA);
}

// Round 10
// 317.692 us; speedup vs baseline: 1.1155x; 1.1155x over previous
//
#include <hip/hip_runtime.h>
#include <hip/hip_bf16.h>

#define N_ROWS 262144
#define IN_DIM 64
#define HID 256
#define EMB 128
#define OUT_DIM 64
#define NSEG 1024
#define ROWS_B 128         // rows per block in k1/k3
#define MT 8               // row-tiles per wave (ROWS_B/16) -- every wave covers all rows
#define NWAVE 8            // waves per block (512 threads)
#define LDS_S 264          // halves per LDS row (256 + 8 pad -> stride 33 slots == 1 mod 8: uniform banks)
#define CHUNK 1024         // rows per k_scatter block
#define NSLOTS (2 * (N_ROWS / CHUNK))   // 512 partial slots

typedef _Float16 h16;
typedef _Float16 h16x8 __attribute__((ext_vector_type(8)));
typedef _Float16 h16x4 __attribute__((ext_vector_type(4)));
typedef float f32x4 __attribute__((ext_vector_type(4)));

// ---------------- prep kernels (round-6 proven versions) ----------------

__global__ void k_max(const int* __restrict__ aisle, int* __restrict__ maxA) {
    int v = 0;
    for (int i = blockIdx.x * blockDim.x + threadIdx.x; i < N_ROWS; i += gridDim.x * blockDim.x)
        v = max(v, aisle[i]);
#pragma unroll
    for (int off = 32; off > 0; off >>= 1) v = max(v, __shfl_down(v, off));
    __shared__ int red[4];
    if ((threadIdx.x & 63) == 0) red[threadIdx.x >> 6] = v;
    __syncthreads();
    if (threadIdx.x == 0) {
        int m = red[0];
        for (int i = 1; i < 4; ++i) m = max(m, red[i]);
        atomicMax(maxA, m);
    }
}

// Fragment-order weight layout: for n-tile t, k-step kt, the 64 lanes' h16x8
// fragments are CONTIGUOUS: halves offset = t*16*K + kt*512 + lane*8, where
// lane = l4*16 + l15 and the fragment holds W[k = kt*32 + l4*8 + j][n = t*16 + l15].
// A wave's (t,kt) load is one contiguous 1024B chunk -> perfectly coalesced.
__device__ __forceinline__ void frag_nk(int o, int K, int& n, int& k) {
    int tile = o / (16 * K);
    int r = o - tile * 16 * K;
    n = tile * 16 + ((r >> 3) & 15);
    k = (r >> 9) * 32 + (((r >> 7) & 3) << 3) + (r & 7);
}

__global__ void k_prep_weights(const float* __restrict__ W1, const float* __restrict__ W2,
                               const float* __restrict__ W3, const float* __restrict__ A1f,
                               const float* __restrict__ A2f, const float* __restrict__ A3f,
                               h16* __restrict__ W1t, h16* __restrict__ W2t, h16* __restrict__ W3t,
                               h16* __restrict__ A1t, h16* __restrict__ A2t, h16* __restrict__ A3t) {
    int idx = blockIdx.x * 256 + threadIdx.x;      // total 262144 threads
    int n, k;
    if (idx < 16384)       { int o = idx;          frag_nk(o, 64, n, k);  W1t[o] = (h16)W1[k * 256 + n]; }
    else if (idx < 81920)  { int o = idx - 16384;  frag_nk(o, 256, n, k); W2t[o] = (h16)W2[k * 256 + n]; }
    else if (idx < 114688) { int o = idx - 81920;  frag_nk(o, 256, n, k); W3t[o] = (h16)W3[k * 128 + n]; }
    else if (idx < 180224) { int o = idx - 114688; frag_nk(o, 256, n, k); A1t[o] = (h16)A1f[k * 256 + n]; }
    else if (idx < 245760) { int o = idx - 180224; frag_nk(o, 256, n, k); A2t[o] = (h16)A2f[k * 256 + n]; }
    else                   { int o = idx - 245760; frag_nk(o, 256, n, k); A3t[o] = (h16)A3f[k * 64  + n]; }
}

// ---------------- fused MLP layer, IN-PLACE, 8 waves x (128 rows x 32 cols) ----------------
// S: [128 rows][K] fp16, stride LDS_S. Computes lrelu?(S @ W^T + bias) back into S.
// Every wave reads ALL rows/k of S, then barrier, then epilogue overwrites its
// 32-col slice, then barrier. Weights in fragment-order: wave's (nt,kt) fragment
// load = contiguous 1024B, depth-3 prefetched (covers L2 latency).
// Swapped-operand MFMA: mfma(w, a, acc) -> D[n][m].
template <int K, int NOUT, bool ACT>
__device__ __forceinline__ void mlp_layer_ip(const h16* __restrict__ Wt,
                                             const float* __restrict__ bias,
                                             h16* __restrict__ S,
                                             int lane, int wave) {
    constexpr int NW = NOUT / NWAVE;   // cols per wave (32)
    constexpr int NT = NW / 16;        // n-tiles per wave (2)
    constexpr int KT = K / 32;         // k-steps
    const int l15 = lane & 15, l4 = lane >> 4;
    f32x4 acc[MT][NT];
#pragma unroll
    for (int mt = 0; mt < MT; ++mt)
#pragma unroll
        for (int nt = 0; nt < NT; ++nt)
#pragma unroll
            for (int j = 0; j < 4; ++j) acc[mt][nt][j] = 0.f;

    const h16* wb[NT];
#pragma unroll
    for (int nt = 0; nt < NT; ++nt)
        wb[nt] = Wt + (size_t)(wave * NT + nt) * 16 * K + lane * 8;

    h16x8 b0[NT], b1[NT], b2[NT];
#pragma unroll
    for (int nt = 0; nt < NT; ++nt) b0[nt] = *(const h16x8*)wb[nt];
    if (KT > 1) {
#pragma unroll
        for (int nt = 0; nt < NT; ++nt) b1[nt] = *(const h16x8*)(wb[nt] + 512);
    }
    if (KT > 2) {
#pragma unroll
        for (int nt = 0; nt < NT; ++nt) b2[nt] = *(const h16x8*)(wb[nt] + 1024);
    }

#pragma unroll
    for (int kt = 0; kt < KT; ++kt) {
        h16x8 bc[NT];
#pragma unroll
        for (int nt = 0; nt < NT; ++nt) bc[nt] = b0[nt];
#pragma unroll
        for (int nt = 0; nt < NT; ++nt) b0[nt] = b1[nt];
#pragma unroll
        for (int nt = 0; nt < NT; ++nt) b1[nt] = b2[nt];
        if (kt + 3 < KT) {
#pragma unroll
            for (int nt = 0; nt < NT; ++nt) b2[nt] = *(const h16x8*)(wb[nt] + (kt + 3) * 512);
        }
        __builtin_amdgcn_s_setprio(1);
#pragma unroll
        for (int mt = 0; mt < MT; ++mt) {
            h16x8 a = *(const h16x8*)&S[(mt * 16 + l15) * LDS_S + kt * 32 + l4 * 8];
#pragma unroll
            for (int nt = 0; nt < NT; ++nt)
                acc[mt][nt] = __builtin_amdgcn_mfma_f32_16x16x32_f16(bc[nt], a, acc[mt][nt], 0, 0, 0);
        }
        __builtin_amdgcn_s_setprio(0);
    }

    __syncthreads();   // all reads of S complete across the block

#pragma unroll
    for (int nt = 0; nt < NT; ++nt) {
        const int cb = wave * NW + nt * 16 + l4 * 4;
        const f32x4 bias4 = *(const f32x4*)&bias[cb];
#pragma unroll
        for (int mt = 0; mt < MT; ++mt) {
            f32x4 v = acc[mt][nt] + bias4;
            if (ACT) {
#pragma unroll
                for (int j = 0; j < 4; ++j) v[j] = fmaxf(v[j], 0.01f * v[j]);
            }
            h16x4 hv;
#pragma unroll
            for (int j = 0; j < 4; ++j) hv[j] = (h16)v[j];
            *(h16x4*)&S[(mt * 16 + l15) * LDS_S + cb] = hv;
        }
    }
    __syncthreads();   // new acts visible
}

// Final k1 layer: K=256 -> 128 cols (16 cols/wave, NT=1), direct global h16 store.
__device__ __forceinline__ void mlp_layer_out_h16(const h16* __restrict__ Wt,
                                                  const float* __restrict__ bias,
                                                  const h16* __restrict__ S,
                                                  h16* __restrict__ gout, int row0,
                                                  int lane, int wave) {
    const int l15 = lane & 15, l4 = lane >> 4;
    f32x4 acc[MT];
#pragma unroll
    for (int mt = 0; mt < MT; ++mt)
#pragma unroll
        for (int j = 0; j < 4; ++j) acc[mt][j] = 0.f;

    const h16* wb = Wt + (size_t)wave * 16 * 256 + lane * 8;
    h16x8 b0 = *(const h16x8*)wb;
    h16x8 b1 = *(const h16x8*)(wb + 512);
    h16x8 b2 = *(const h16x8*)(wb + 1024);
#pragma unroll
    for (int kt = 0; kt < 8; ++kt) {
        h16x8 bc = b0;
        b0 = b1;
        b1 = b2;
        if (kt + 3 < 8) b2 = *(const h16x8*)(wb + (kt + 3) * 512);
        __builtin_amdgcn_s_setprio(1);
#pragma unroll
        for (int mt = 0; mt < MT; ++mt) {
            h16x8 a = *(const h16x8*)&S[(mt * 16 + l15) * LDS_S + kt * 32 + l4 * 8];
            acc[mt] = __builtin_amdgcn_mfma_f32_16x16x32_f16(bc, a, acc[mt], 0, 0, 0);
        }
        __builtin_amdgcn_s_setprio(0);
    }

    const int cb = wave * 16 + l4 * 4;
    const f32x4 bias4 = *(const f32x4*)&bias[cb];
#pragma unroll
    for (int mt = 0; mt < MT; ++mt) {
        f32x4 v = acc[mt] + bias4;
        h16x4 hv;
#pragma unroll
        for (int j = 0; j < 4; ++j) hv[j] = (h16)v[j];
        *(h16x4*)&gout[(size_t)(row0 + mt * 16 + l15) * 128 + cb] = hv;
    }
}

// ---------------- phase 1: x -> h ----------------
__global__ __launch_bounds__(512, 4) void k1(const float* __restrict__ x,
                                             const h16* __restrict__ W1t, const float* __restrict__ b1,
                                             const h16* __restrict__ W2t, const float* __restrict__ b2,
                                             const h16* __restrict__ W3t, const float* __restrict__ b3,
                                             h16* __restrict__ hbuf) {
    __shared__ __align__(16) h16 S[ROWS_B * LDS_S];
    const int tid = threadIdx.x, lane = tid & 63, wave = tid >> 6;
    const int row0 = blockIdx.x * ROWS_B;

    {   // stage x: 512 threads, 4 threads/row, 16 floats each
        const int r = tid >> 2, c16 = (tid & 3) * 16;
        const float* src = &x[(size_t)(row0 + r) * 64 + c16];
        f32x4 v0 = *(const f32x4*)&src[0];
        f32x4 v1 = *(const f32x4*)&src[4];
        f32x4 v2 = *(const f32x4*)&src[8];
        f32x4 v3 = *(const f32x4*)&src[12];
        h16x8 h0, h1;
#pragma unroll
        for (int j = 0; j < 4; ++j) { h0[j] = (h16)v0[j]; h0[4 + j] = (h16)v1[j];
                                      h1[j] = (h16)v2[j]; h1[4 + j] = (h16)v3[j]; }
        *(h16x8*)&S[r * LDS_S + c16]     = h0;
        *(h16x8*)&S[r * LDS_S + c16 + 8] = h1;
    }
    __syncthreads();

    mlp_layer_ip<64, 256, true>(W1t, b1, S, lane, wave);
    mlp_layer_ip<256, 256, true>(W2t, b2, S, lane, wave);
    mlp_layer_out_h16(W3t, b3, S, hbuf, row0, lane, wave);
}

// ---------------- phase 2: counting-sort + owner-computes segment sums ----------------
// 512 threads (8 waves = 2 waves/SIMD at 1 block/CU): 8 threads per aisle x 16
// halves each -> per-thread serial work halved vs 256-thread version, 2x the
// latency hiding. Same algorithm, same slot layout, same traffic.
__global__ __launch_bounds__(512) void k_scatter(const h16* __restrict__ hbuf,
                                                 const int* __restrict__ aisle,
                                                 const int* __restrict__ batch,
                                                 float* __restrict__ partials,
                                                 float* __restrict__ pcount,
                                                 int* __restrict__ bvmap) {
    __shared__ int la[CHUNK], lb[CHUNK], rankv[CHUNK], rowlist[CHUNK];
    __shared__ int hist[128], scan[128];
    const int tid = threadIdx.x;
    const int row0 = blockIdx.x * CHUNK;

    if (tid < 128) hist[tid] = 0;
    for (int i = tid; i < CHUNK; i += 512) { la[i] = aisle[row0 + i]; lb[i] = batch[row0 + i]; }
    __syncthreads();

    const int bLo = lb[0], bHi = lb[CHUNK - 1];

    for (int i = tid; i < CHUNK; i += 512) {
        int slot = min(lb[i] - bLo, 1);
        rankv[i] = atomicAdd(&hist[slot * 64 + la[i]], 1);
    }
    __syncthreads();
    if (tid < 128) scan[tid] = hist[tid];
    __syncthreads();
#pragma unroll
    for (int st = 1; st < 128; st <<= 1) {
        int v = 0;
        if (tid < 128 && tid >= st) v = scan[tid - st];
        __syncthreads();
        if (tid < 128) scan[tid] += v;
        __syncthreads();
    }
    for (int i = tid; i < CHUNK; i += 512) {
        int bin = min(lb[i] - bLo, 1) * 64 + la[i];
        rowlist[scan[bin] - hist[bin] + rankv[i]] = i;
    }
    __syncthreads();

    const int a_own = tid >> 3, cg = tid & 7;   // 64 aisles x 8 threads x 16 halves
    for (int slot = 0; slot < 2; ++slot) {
        const int sid = blockIdx.x * 2 + slot;
        const int bv = bLo + slot;
        if (bv > bHi) { if (tid == 0) bvmap[sid] = -1; continue; }

        const int bin = slot * 64 + a_own;
        const int s1 = scan[bin];
        const int s0 = s1 - hist[bin];

        float acc[16];
#pragma unroll
        for (int j = 0; j < 16; ++j) acc[j] = 0.f;

        for (int idx = s0; idx < s1; ++idx) {
            const int r = rowlist[idx];
            const h16x8* src = (const h16x8*)&hbuf[(size_t)(row0 + r) * 128 + cg * 16];
            h16x8 v0 = src[0], v1 = src[1];
#pragma unroll
            for (int j = 0; j < 8; ++j) {
                acc[j]     += (float)v0[j];
                acc[8 + j] += (float)v1[j];
            }
        }
        float* dst = &partials[(size_t)sid * 8192 + a_own * 128 + cg * 16];
#pragma unroll
        for (int g2 = 0; g2 < 4; ++g2) *(f32x4*)&dst[g2 * 4] = *(const f32x4*)&acc[g2 * 4];
        if (cg == 0) pcount[sid * 64 + a_own] = (float)(s1 - s0);
        if (tid == 0) bvmap[sid] = bv;
    }
}

// ---------------- phase 2b: reduce partials -> fp16 means ----------------
// bvmap is monotone (batch sorted) -> matching slots contiguous; find [lo,hi)
// with a parallel scan, then loop only that window (~35 vs 512 slots).
__global__ __launch_bounds__(128) void k_means(const float* __restrict__ partials,
                                               const float* __restrict__ pcount,
                                               const int* __restrict__ bvmap,
                                               h16* __restrict__ means,
                                               const int* __restrict__ maxA) {
    __shared__ int sbv[NSLOTS];
    __shared__ int lohi[2];
    const int b = blockIdx.x >> 6, a = blockIdx.x & 63;
    const int tid = threadIdx.x;
    const int mult = *maxA + 1;
    for (int i = tid; i < NSLOTS; i += 128) sbv[i] = bvmap[i];
    if (tid == 0) { lohi[0] = NSLOTS; lohi[1] = 0; }
    __syncthreads();
    int llo = NSLOTS, lhi = 0;
#pragma unroll
    for (int q = 0; q < 4; ++q) {
        const int i = tid * 4 + q;
        if (sbv[i] == b) { if (i < llo) llo = i; lhi = i + 1; }
    }
    if (llo < NSLOTS) atomicMin(&lohi[0], llo);
    if (lhi > 0)      atomicMax(&lohi[1], lhi);
    __syncthreads();
    if (a >= mult) return;

    float sum = 0.f, cnt = 0.f;
    for (int s = lohi[0]; s < lohi[1]; ++s) {
        if (sbv[s] == b) {
            sum += partials[(size_t)s * 8192 + a * 128 + tid];
            cnt += pcount[s * 64 + a];   // broadcast load
        }
    }
    means[(size_t)(b * mult + a) * 128 + tid] = (h16)(sum / fmaxf(cnt, 1.0f));
}

// ---------------- phase 3: concat(h, mean) -> out ----------------
__global__ __launch_bounds__(512, 4) void k3(const h16* __restrict__ hbuf,
                                             const int* __restrict__ aisle,
                                             const int* __restrict__ batch,
                                             const h16* __restrict__ means,
                                             const h16* __restrict__ A1t, const float* __restrict__ c1,
                                             const h16* __restrict__ A2t, const float* __restrict__ c2,
                                             const h16* __restrict__ A3t, const float* __restrict__ c3,
                                             float* __restrict__ out, const int* __restrict__ maxA) {
    __shared__ __align__(16) h16 S[ROWS_B * LDS_S];
    const int tid = threadIdx.x, lane = tid & 63, wave = tid >> 6;
    const int row0 = blockIdx.x * ROWS_B;
    const int mult = *maxA + 1;

    {   // stage h (128 halves) + mean (128 halves) per row; 4 threads/row, 32 halves each
        const int r = tid >> 2, p = tid & 3;
        const int g = row0 + r;
        const h16x8* hs = (const h16x8*)&hbuf[(size_t)g * 128 + p * 32];
        h16x8* hd = (h16x8*)&S[r * LDS_S + p * 32];
        hd[0] = hs[0]; hd[1] = hs[1]; hd[2] = hs[2]; hd[3] = hs[3];
        const int id = aisle[g] + batch[g] * mult;
        const h16x8* ms = (const h16x8*)&means[(size_t)id * 128 + p * 32];
        h16x8* md = (h16x8*)&S[r * LDS_S + 128 + p * 32];
        md[0] = ms[0]; md[1] = ms[1]; md[2] = ms[2]; md[3] = ms[3];
    }
    __syncthreads();

    mlp_layer_ip<256, 256, true>(A1t, c1, S, lane, wave);
    mlp_layer_ip<256, 256, true>(A2t, c2, S, lane, wave);

    // final layer: K=256 -> 64 cols; 4 col-tiles x 2 k-halves across 8 waves,
    // f32 LDS reduce, fp32 f32x4 stores
    {
        const int l15 = lane & 15, l4 = lane >> 4;
        const int w4 = wave & 3, kw = wave >> 2;
        f32x4 acc4[MT];
#pragma unroll
        for (int mt = 0; mt < MT; ++mt)
#pragma unroll
            for (int j = 0; j < 4; ++j) acc4[mt][j] = 0.f;

        // frag-order: tile w4 base + k-half kw (4 k-steps of 512 halves each)
        const h16* wb = A3t + (size_t)w4 * 16 * 256 + (size_t)kw * 4 * 512 + lane * 8;
        h16x8 b0 = *(const h16x8*)wb;
        h16x8 b1 = *(const h16x8*)(wb + 512);
        h16x8 b2 = *(const h16x8*)(wb + 1024);
#pragma unroll
        for (int kt = 0; kt < 4; ++kt) {
            h16x8 bc = b0;
            b0 = b1;
            b1 = b2;
            if (kt + 3 < 4) b2 = *(const h16x8*)(wb + (kt + 3) * 512);
            __builtin_amdgcn_s_setprio(1);
#pragma unroll
            for (int mt = 0; mt < MT; ++mt) {
                h16x8 a = *(const h16x8*)&S[(mt * 16 + l15) * LDS_S + kw * 128 + kt * 32 + l4 * 8];
                acc4[mt] = __builtin_amdgcn_mfma_f32_16x16x32_f16(bc, a, acc4[mt], 0, 0, 0);
            }
            __builtin_amdgcn_s_setprio(0);
        }
        __syncthreads();   // all S reads done; S reused as f32 scratch [128][68]
        float* fS = (float*)S;
        if (kw == 1) {
#pragma unroll
            for (int mt = 0; mt < MT; ++mt) {
                const int row = mt * 16 + l15;
                *(f32x4*)&fS[row * 68 + w4 * 16 + l4 * 4] = acc4[mt];
            }
        }
        __syncthreads();
        if (kw == 0) {
            const f32x4 bias4 = *(const f32x4*)&c3[w4 * 16 + l4 * 4];
#pragma unroll
            for (int mt = 0; mt < MT; ++mt) {
                const int row = mt * 16 + l15;
                f32x4 p = *(const f32x4*)&fS[row * 68 + w4 * 16 + l4 * 4];
                f32x4 v = acc4[mt] + p + bias4;
                *(f32x4*)&out[(size_t)(row0 + row) * 64 + w4 * 16 + l4 * 4] = v;
            }
        }
    }
}

// ---------------- host launch ----------------
extern "C" void kernel_launch(void* const* d_in, const int* in_sizes, int n_in,
                              void* d_out, int out_size, void* d_ws, size_t ws_size,
                              hipStream_t stream) {
    const float* x     = (const float*)d_in[0];
    const int*   aisle = (const int*)d_in[1];
    const int*   batch = (const int*)d_in[2];
    const float* W1 = (const float*)d_in[3];  const float* b1 = (const float*)d_in[4];
    const float* W2 = (const float*)d_in[5];  const float* b2 = (const float*)d_in[6];
    const float* W3 = (const float*)d_in[7];  const float* b3 = (const float*)d_in[8];
    const float* A1 = (const float*)d_in[9];  const float* c1 = (const float*)d_in[10];
    const float* A2 = (const float*)d_in[11]; const float* c2 = (const float*)d_in[12];
    const float* A3 = (const float*)d_in[13]; const float* c3 = (const float*)d_in[14];
    float* out = (float*)d_out;

    char* w = (char*)d_ws;
    size_t off = 0;
    h16*   hbuf     = (h16*)(w + off);   off += (size_t)N_ROWS * 128 * sizeof(h16);       // 64 MB
    float* partials = (float*)(w + off); off += (size_t)NSLOTS * 8192 * sizeof(float);    // 16 MB
    float* pcount   = (float*)(w + off); off += NSLOTS * 64 * sizeof(float);
    int*   bvmap    = (int*)(w + off);   off += NSLOTS * sizeof(int);
    h16*   means    = (h16*)(w + off);   off += NSEG * 128 * sizeof(h16);
    h16*   W1t      = (h16*)(w + off);   off += 16384 * sizeof(h16);
    h16*   W2t      = (h16*)(w + off);   off += 65536 * sizeof(h16);
    h16*   W3t      = (h16*)(w + off);   off += 32768 * sizeof(h16);
    h16*   A1t      = (h16*)(w + off);   off += 65536 * sizeof(h16);
    h16*   A2t      = (h16*)(w + off);   off += 65536 * sizeof(h16);
    h16*   A3t      = (h16*)(w + off);   off += 16384 * sizeof(h16);
    int*   maxA     = (int*)(w + off);   off += 256;

    hipMemsetAsync(maxA, 0, sizeof(int), stream);

    k_max<<<256, 256, 0, stream>>>(aisle, maxA);
    k_prep_weights<<<1024, 256, 0, stream>>>(W1, W2, W3, A1, A2, A3, W1t, W2t, W3t, A1t, A2t, A3t);
    k1<<<N_ROWS / ROWS_B, 512, 0, stream>>>(x, W1t, b1, W2t, b2, W3t, b3, hbuf);
    k_scatter<<<N_ROWS / CHUNK, 512, 0, stream>>>(hbuf, aisle, batch, partials, pcount, bvmap);
    k_means<<<16 * 64, 128, 0, stream>>>(partials, pcount, bvmap, means, maxA);
    k3<<<N_ROWS / ROWS_B, 512, 0, stream>>>(hbuf, aisle, batch, means, A1t, c1, A2t, c2, A3t, c3,
                                            out, maxA);
}